// Round 6
// baseline (582.102 us; speedup 1.0000x reference)
//
#include <hip/hip_runtime.h>

// BoneLengthLoss: masked MSE over 32 bone lengths, B=524288, 37 kpts, fp32.
// ~485 MB input stream; FETCH shows ~265 MB HBM (L3 holds ~one array) ->
// floor somewhere in 50-90us.
//
// Mechanism matrix (all ~210-220us, 2.2 TB/s): shallow/deep x glds/reg
// (R1-R8; reg variants scratch-proof, WRITE~0, VGPR 108). Outstanding depth
// and staging mechanism are exonerated; every cell shares the block-phased
// barrier-lockstep structure at 2 blocks/CU. R9 (bpermute, no-LDS) failed
// correctness -> structural hypothesis still untested.
// R10 (this): safe structural discriminator. One wave per ROW-PAIR (222
// contiguous floats -> coalesced float2 loads), lane=(bone,row-half), each
// lane computes its bone fully locally from a WAVE-PRIVATE 1.8KB LDS slice.
// No cross-wave sharing -> ZERO barriers; intra-wave ds ordering is
// compiler-enforced. __launch_bounds__(256,8): 32 free-running waves/CU
// (pure TLP, m13's regime) vs R1-R8's 8-12 lockstepped. num/den
// single-counted -> exact reference semantics, no cross-lane ops.

#define NKPT   37
#define ROWF   111              // floats per pose row
#define BLOCK  256
#define WPB    4
#define GRID   2048             // 8 blocks/CU x 256 CU
#define NWAVES (GRID * WPB)     // 8192 waves; 262144/8192 = 32 pairs/wave exact

__device__ const unsigned char dJ1[32] = {1,1,1,2,3,11,11,12,13,14,15,16,12,18,20,13,19,21,16,16,24,25,24,27,29,25,28,30,17,33,34,35};
__device__ const unsigned char dJ2[32] = {2,3,4,5,6,12,13,14,14,15,16,17,18,20,22,19,21,23,24,25,26,26,27,29,31,28,30,32,33,34,35,36};

// ws[0]=num(f32) ws[1]=den(u32) ws[2]=mask-layout flag ws[3]=done counter
__global__ void init_detect(const unsigned int* __restrict__ mw,
                            unsigned int* __restrict__ ws) {
    const int tid = threadIdx.x;
    if (tid < 4) ws[tid] = 0u;
    __syncthreads();
    unsigned int local = 0;
    for (int i = tid; i < 1024; i += BLOCK) local |= mw[i] & 0xFFFFFF00u;
    if (__any(local != 0) && (tid & 63) == 0) atomicOr(&ws[2], 1u);
}

// Per row-pair, per lane: 4 coalesced float2 global loads + 2 mask loads,
// 4 ds_write_b64 into the wave-private slice, 12 ds_read_b32 (endpoint
// floats by compile-time-table index), ~30 VALU. No barriers anywhere.
template <bool MB>
__device__ __forceinline__ void stream_pairs(
        const float2* __restrict__ p2, const float2* __restrict__ q2,
        const unsigned char* __restrict__ mb8, const int* __restrict__ mi,
        int npairs, int gw, int lane, int laneB,
        int o1, int o2, int moff1, int moff2,
        float* __restrict__ sp, float* __restrict__ sq,
        float& num, unsigned int& den) {
    float2* sp2 = (float2*)sp;
    float2* sq2 = (float2*)sq;
    for (int pr = gw; pr < npairs; pr += NWAVES) {
        const float2* pb_ = p2 + (size_t)pr * ROWF;   // pair = 111 float2
        const float2* qb_ = q2 + (size_t)pr * ROWF;
        float2 a0 = pb_[lane];
        float2 a1 = pb_[laneB];
        float2 b0 = qb_[lane];
        float2 b1 = qb_[laneB];
        unsigned int m1, m2;
        if (MB) {
            const unsigned char* mrow = mb8 + (size_t)pr * (2 * NKPT);
            m1 = (unsigned int)mrow[moff1];
            m2 = (unsigned int)mrow[moff2];
        } else {
            const int* mrow = mi + (size_t)pr * (2 * NKPT);
            m1 = ((unsigned int)mrow[moff1]) & 1u;
            m2 = ((unsigned int)mrow[moff2]) & 1u;
        }
        // Stage into the wave-private slice (clamped lanes 47..63 write the
        // same value to element 110 -- benign). Compiler inserts the vmcnt
        // waits here and lgkmcnt before the dependent reads below.
        sp2[lane] = a0; sp2[laneB] = a1;
        sq2[lane] = b0; sq2[laneB] = b1;

        float p1x = sp[o1], p1y = sp[o1 + 1], p1z = sp[o1 + 2];
        float p2x = sp[o2], p2y = sp[o2 + 1], p2z = sp[o2 + 2];
        float q1x = sq[o1], q1y = sq[o1 + 1], q1z = sq[o1 + 2];
        float q2x = sq[o2], q2y = sq[o2 + 1], q2z = sq[o2 + 2];

        float pdx = p2x - p1x, pdy = p2y - p1y, pdz = p2z - p1z;
        float qdx = q2x - q1x, qdy = q2y - q1y, qdz = q2z - q1z;
        float pl = __builtin_amdgcn_sqrtf(pdx * pdx + pdy * pdy + pdz * pdz);
        float ql = __builtin_amdgcn_sqrtf(qdx * qdx + qdy * qdy + qdz * qdz);
        unsigned int v = m1 & m2 & 1u;
        float dd = pl - ql;
        num += v ? dd * dd : 0.0f;
        den += v;
    }
}

__global__ __launch_bounds__(BLOCK, 8)
void bone_main(const float* __restrict__ pred, const float* __restrict__ ref,
               const void* __restrict__ mask, int B,
               unsigned int* __restrict__ ws, float* __restrict__ out) {
    __shared__ __align__(16) float s_p[WPB][224];   // 224 >= 222 floats/pair
    __shared__ __align__(16) float s_q[WPB][224];   // total pose LDS: 7168 B
    __shared__ float s_rn[WPB];
    __shared__ unsigned int s_rd[WPB];

    const int tid  = threadIdx.x;
    const int wave = tid >> 6;
    const int lane = tid & 63;
    const int laneB = (lane < 47) ? 64 + lane : 110;  // float2 idx 64..110
    const int b = lane & 31;                          // bone
    const int h = lane >> 5;                          // row within the pair

    const int j1 = (int)dJ1[b], j2 = (int)dJ2[b];
    const int o1 = h * ROWF + 3 * j1;                 // float offsets in slice
    const int o2 = h * ROWF + 3 * j2;
    const int moff1 = h * NKPT + j1;                  // mask offsets in pair
    const int moff2 = h * NKPT + j2;

    const bool mask_bytes = (ws[2] != 0);
    const int npairs = B >> 1;                        // 262144
    const int gw = blockIdx.x * WPB + wave;

    const float2* __restrict__ p2 = (const float2*)pred;
    const float2* __restrict__ q2 = (const float2*)ref;
    const unsigned char* __restrict__ mb8 = (const unsigned char*)mask;
    const int* __restrict__ mi = (const int*)mask;

    float num = 0.0f;
    unsigned int den = 0u;

    if (mask_bytes)
        stream_pairs<true>(p2, q2, mb8, mi, npairs, gw, lane, laneB,
                           o1, o2, moff1, moff2, s_p[wave], s_q[wave],
                           num, den);
    else
        stream_pairs<false>(p2, q2, mb8, mi, npairs, gw, lane, laneB,
                            o1, o2, moff1, moff2, s_p[wave], s_q[wave],
                            num, den);

    // ---- reduce: wave shuffle -> block partials -> one atomic per block ----
#pragma unroll
    for (int off = 32; off > 0; off >>= 1) {
        num += __shfl_down(num, off, 64);
        den += __shfl_down(den, off, 64);
    }
    if (lane == 0) { s_rn[wave] = num; s_rd[wave] = den; }
    __syncthreads();
    if (tid == 0) {
        float n = s_rn[0] + s_rn[1] + s_rn[2] + s_rn[3];
        unsigned int d = s_rd[0] + s_rd[1] + s_rd[2] + s_rd[3];
        atomicAdd((float*)&ws[0], n);
        atomicAdd(&ws[1], d);
        __threadfence();
        unsigned int prev = atomicAdd(&ws[3], 1u);
        if (prev == (unsigned int)(gridDim.x - 1)) {
            float fn = atomicAdd((float*)&ws[0], 0.0f);
            unsigned int fd = atomicAdd(&ws[1], 0u);
            out[0] = fn / (float)fd;
        }
    }
}

extern "C" void kernel_launch(void* const* d_in, const int* in_sizes, int n_in,
                              void* d_out, int out_size, void* d_ws, size_t ws_size,
                              hipStream_t stream) {
    const float* pred = (const float*)d_in[0];
    const float* ref  = (const float*)d_in[1];
    const void*  mask = d_in[2];
    const int n_mask  = in_sizes[2];           // 524288 * 37 elements
    const int B       = n_mask / NKPT;
    unsigned int* ws  = (unsigned int*)d_ws;

    init_detect<<<1, BLOCK, 0, stream>>>((const unsigned int*)mask, ws);
    bone_main<<<GRID, BLOCK, 0, stream>>>(pred, ref, mask, B, ws, (float*)d_out);
}

// Round 7
// 555.316 us; speedup vs baseline: 1.0482x; 1.0482x over previous
//
#include <hip/hip_runtime.h>

// BoneLengthLoss: masked MSE over 32 bone lengths, B=524288, 37 kpts, fp32.
// ~485 MB logical read per dispatch.
//
// Closed mechanism matrix (R1-R10, all 210-250us, ~2.2 TB/s delivered):
// glds/reg/LDS-roundtrip staging, 1-3-tile pipelines, barriers vs
// free-running, 8-20 waves/CU, grid 512-2048 -- ALL flat. FETCH ~270MB
// (L3 retains ~220MB across dispatches) with HBM at 15% and L3 ~1TB/s:
// both loafing, sum pinned. Best-fit model: per-XCD L2<->fabric port
// ~128 B/cyc -> ~2.45 TB/s device cap on CU-bound fill traffic; we sit
// at ~90% of it.
// R11 (this): last discriminator on the 219us R8 structure. (a) pose
// loads NON-TEMPORAL (no L2/L3 allocate) -- fabric-cap theory predicts
// no change, L3-allocation theory predicts a win, additive-L3 theory
// predicts a regression; (b) ONE STREAM PER WAVE: wave 0,1 read pred
// halves, wave 2,3 read ref halves (contiguous 3.5KB span each) instead
// of two interleaved streams 232MB apart. Same 17 loads/wave, same
// A/B register double-buffer (scratch-proof named locals).

#define NKPT   37
#define ROWF   111             // floats per pose row
#define TROWS  64              // rows per tile (= lane)
#define TF4    1776            // float4 per tile per array (64*111/4)
#define HF4    888             // float4 per wave (half a tile of one array)
#define TMB    2368            // mask bytes per tile
#define TMW    592             // mask words per tile
#define WMW    148             // mask words per wave (2*64 + 20)
#define BLOCK  256
#define WPB    4
#define GRID   512             // 2 blocks/CU * 256 CU; 8192/512 = 16 tiles exact

constexpr int J1[32] = {1,1,1,2,3,11,11,12,13,14,15,16,12,18,20,13,19,21,16,16,24,25,24,27,29,25,28,30,17,33,34,35};
constexpr int J2[32] = {2,3,4,5,6,12,13,14,14,15,16,17,18,20,22,19,21,23,24,25,26,26,27,29,31,28,30,32,33,34,35,36};

typedef float __attribute__((ext_vector_type(4))) f4v;

#define LGKM0() asm volatile("s_waitcnt lgkmcnt(0)" ::: "memory")
#define BAR()   __builtin_amdgcn_s_barrier()
#define NTL(p)  __builtin_nontemporal_load((const f4v*)(p))

// ws[0]=num(f32) ws[1]=den(u32) ws[2]=mask-layout flag ws[3]=done counter
__global__ void init_detect(const unsigned int* __restrict__ mw,
                            unsigned int* __restrict__ ws) {
    const int tid = threadIdx.x;
    if (tid < 4) ws[tid] = 0u;
    __syncthreads();
    unsigned int local = 0;
    for (int i = tid; i < 1024; i += BLOCK) local |= mw[i] & 0xFFFFFF00u;
    if (__any(local != 0) && (tid & 63) == 0) atomicOr(&ws[2], 1u);
}

// Merged lens+acc: pred and ref rows both live in LDS. All offsets
// compile-time; endpoint reads CSE'd by the compiler.
template <int G>
__device__ __forceinline__ void do_tile(const float* __restrict__ sp,
                                        const float* __restrict__ sq,
                                        const unsigned char* __restrict__ sm,
                                        float& num, unsigned int& den) {
#pragma unroll
    for (int k = 0; k < 8; ++k) {
        const int a = J1[G * 8 + k], b = J2[G * 8 + k];
        const int a3 = a * 3, b3 = b * 3;
        float pdx = sp[b3] - sp[a3];
        float pdy = sp[b3 + 1] - sp[a3 + 1];
        float pdz = sp[b3 + 2] - sp[a3 + 2];
        float qdx = sq[b3] - sq[a3];
        float qdy = sq[b3 + 1] - sq[a3 + 1];
        float qdz = sq[b3 + 2] - sq[a3 + 2];
        float pl = __builtin_amdgcn_sqrtf(pdx * pdx + pdy * pdy + pdz * pdz);
        float ql = __builtin_amdgcn_sqrtf(qdx * qdx + qdy * qdy + qdz * qdz);
        unsigned int v = (unsigned int)(sm[a] & sm[b]);
        float d = pl - ql;
        num += v ? d * d : 0.0f;
        den += v;
    }
}

#define COMPUTE() do { switch (wave) { \
    case 0: do_tile<0>(sp_row, sq_row, sm_row, num, den); break; \
    case 1: do_tile<1>(sp_row, sq_row, sm_row, num, den); break; \
    case 2: do_tile<2>(sp_row, sq_row, sm_row, num, den); break; \
    default: do_tile<3>(sp_row, sq_row, sm_row, num, den); break; } } while (0)

// 14 nontemporal pose loads (one contiguous 3.5KB span of ONE array) + 3
// cached mask loads per wave, into buffer-suffixed named locals. All
// variables unconditionally defined (tail addrs clamped; stores masked).
#define LD(t, S) do { \
    const f4v* b_ = src4 + (size_t)(t) * TF4 + half888; \
    const unsigned int* mb = mw + (size_t)(t) * TMW + wave * WMW; \
    p0##S  = NTL(b_ + lane);        p1##S  = NTL(b_ + 64  + lane); \
    p2##S  = NTL(b_ + 128 + lane);  p3##S  = NTL(b_ + 192 + lane); \
    p4##S  = NTL(b_ + 256 + lane);  p5##S  = NTL(b_ + 320 + lane); \
    p6##S  = NTL(b_ + 384 + lane);  p7##S  = NTL(b_ + 448 + lane); \
    p8##S  = NTL(b_ + 512 + lane);  p9##S  = NTL(b_ + 576 + lane); \
    p10##S = NTL(b_ + 640 + lane);  p11##S = NTL(b_ + 704 + lane); \
    p12##S = NTL(b_ + 768 + lane);  p13##S = NTL(b_ + 832 + laneT); \
    m0##S = mb[lane]; m1##S = mb[64 + lane]; m2##S = mb[128 + lanem]; \
} while (0)

// ds_write one buffer. Compiler inserts counted vmcnt waits for exactly the
// loads feeding these stores (issued two full phases earlier).
#define ST(S) do { \
    dstw[lane]       = p0##S;   dstw[64  + lane] = p1##S; \
    dstw[128 + lane] = p2##S;   dstw[192 + lane] = p3##S; \
    dstw[256 + lane] = p4##S;   dstw[320 + lane] = p5##S; \
    dstw[384 + lane] = p6##S;   dstw[448 + lane] = p7##S; \
    dstw[512 + lane] = p8##S;   dstw[576 + lane] = p9##S; \
    dstw[640 + lane] = p10##S;  dstw[704 + lane] = p11##S; \
    dstw[768 + lane] = p12##S; \
    if (lane < 56) dstw[832 + lane] = p13##S; \
    smw[lane] = m0##S; smw[64 + lane] = m1##S; \
    if (lane < 20) smw[128 + lane] = m2##S; \
} while (0)

__global__ __launch_bounds__(BLOCK, 2)
void bone_main(const float* __restrict__ pred, const float* __restrict__ ref,
               const void* __restrict__ mask, int B,
               unsigned int* __restrict__ ws, float* __restrict__ out) {
    __shared__ __align__(16) f4v s_pred[TF4];               // 28416 B
    __shared__ __align__(16) f4v s_ref[TF4];                // 28416 B
    __shared__ __align__(16) unsigned int s_maskw[TMW];     //  2368 B
    __shared__ float s_rn[WPB];
    __shared__ unsigned int s_rd[WPB];

    const int tid  = threadIdx.x;
    const int wave = tid >> 6;
    const int lane = tid & 63;                 // = row within the 64-row tile
    const int laneT = (lane < 56) ? lane : 55; // clamped tail indices
    const int lanem = (lane < 20) ? lane : 19;

    const bool mask_bytes = (ws[2] != 0);
    const int ntiles = B / TROWS;              // 8192

    const f4v* __restrict__ pred4 = (const f4v*)pred;
    const f4v* __restrict__ ref4  = (const f4v*)ref;
    const unsigned int* __restrict__ mw = (const unsigned int*)mask;
    const int* __restrict__ mi = (const int*)mask;

    // One stream per wave: waves 0,1 = pred halves; waves 2,3 = ref halves.
    const f4v* src4 = (wave < 2) ? pred4 : ref4;
    const int half888 = (wave & 1) * HF4;
    f4v* dstw = ((wave < 2) ? s_pred : s_ref) + half888;
    unsigned int* smw = s_maskw + wave * WMW;

    const float* sp_row = (const float*)s_pred + lane * ROWF;
    const float* sq_row = (const float*)s_ref  + lane * ROWF;
    const unsigned char* sm_row = (const unsigned char*)s_maskw + lane * NKPT;

    float num = 0.0f;
    unsigned int den = 0u;

    const int bid = blockIdx.x;
    const int ntb = (bid < ntiles) ? (ntiles - bid + GRID - 1) / GRID : 0;

    if (mask_bytes && ntb >= 2 && (ntb & 1) == 0) {
        // ---- two-deep register pipeline (named locals only) ----
        f4v p0A, p1A, p2A, p3A, p4A, p5A, p6A, p7A, p8A, p9A, p10A, p11A, p12A, p13A;
        f4v p0B, p1B, p2B, p3B, p4B, p5B, p6B, p7B, p8B, p9B, p10B, p11B, p12B, p13B;
        unsigned int m0A, m1A, m2A, m0B, m1B, m2B;

        LD(bid, A);                              // T_0 in flight
        LD(bid + GRID, B);                       // T_1 in flight
        for (int j = 0; j < ntb; j += 2) {
            ST(A);                               // waits T_j; T_{j+1} in flight
            { int tn = bid + (j + 2) * GRID;
              if (tn < ntiles) LD(tn, A); }      // T_{j+2} in flight
            LGKM0(); BAR();                      // LDS = T_j visible
            COMPUTE();
            LGKM0(); BAR();                      // all waves done reading

            ST(B);                               // waits T_{j+1}
            { int tn = bid + (j + 3) * GRID;
              if (tn < ntiles) LD(tn, B); }      // T_{j+3} in flight
            LGKM0(); BAR();                      // LDS = T_{j+1} visible
            COMPUTE();
            LGKM0(); BAR();
        }
    } else {
        // ---- fallback: fully drained, handles both mask layouts ----
        for (int t = bid; t < ntiles; t += GRID) {
            for (int i = tid; i < TF4; i += BLOCK) {
                s_pred[i] = pred4[(size_t)t * TF4 + i];
                s_ref[i]  = ref4[(size_t)t * TF4 + i];
            }
            if (mask_bytes) {
                for (int i = tid; i < TMW; i += BLOCK)
                    s_maskw[i] = mw[(size_t)t * TMW + i];
            } else {
                unsigned char* smb = (unsigned char*)s_maskw;
                const int* mb = mi + (size_t)t * TMB;
                for (int i = tid; i < TMB; i += BLOCK)
                    smb[i] = (unsigned char)mb[i];
            }
            __syncthreads();
            COMPUTE();
            __syncthreads();
        }
    }

    // ---- reduce: wave shuffle -> block partials -> one atomic per block ----
#pragma unroll
    for (int off = 32; off > 0; off >>= 1) {
        num += __shfl_down(num, off, 64);
        den += __shfl_down(den, off, 64);
    }
    if (lane == 0) { s_rn[wave] = num; s_rd[wave] = den; }
    __syncthreads();
    if (tid == 0) {
        float n = s_rn[0] + s_rn[1] + s_rn[2] + s_rn[3];
        unsigned int d = s_rd[0] + s_rd[1] + s_rd[2] + s_rd[3];
        atomicAdd((float*)&ws[0], n);
        atomicAdd(&ws[1], d);
        __threadfence();
        unsigned int prev = atomicAdd(&ws[3], 1u);
        if (prev == (unsigned int)(gridDim.x - 1)) {
            float fn = atomicAdd((float*)&ws[0], 0.0f);
            unsigned int fd = atomicAdd(&ws[1], 0u);
            out[0] = fn / (float)fd;
        }
    }
}

extern "C" void kernel_launch(void* const* d_in, const int* in_sizes, int n_in,
                              void* d_out, int out_size, void* d_ws, size_t ws_size,
                              hipStream_t stream) {
    const float* pred = (const float*)d_in[0];
    const float* ref  = (const float*)d_in[1];
    const void*  mask = d_in[2];
    const int n_mask  = in_sizes[2];           // 524288 * 37 elements
    const int B       = n_mask / NKPT;
    unsigned int* ws  = (unsigned int*)d_ws;

    init_detect<<<1, BLOCK, 0, stream>>>((const unsigned int*)mask, ws);
    bone_main<<<GRID, BLOCK, 0, stream>>>(pred, ref, mask, B, ws, (float*)d_out);
}